// Round 10
// baseline (290.515 us; speedup 1.0000x reference)
//
#include <hip/hip_runtime.h>
#include <math.h>

#define N_CELLS   100000
#define N_CLASSES 50
#define N_GENES   500
#define N_EDGES   600000
#define HID       8
#define NKT       8     // K tiles of 64 (512 padded)
#define NRB       6250  // row-blocks of 16 (exactly N_CELLS/16)
#define NB_FUSED  256   // persistent blocks, 1 per CU (1024 thr)
#define NB_CE     391
#define PROWS     56

typedef __attribute__((ext_vector_type(4))) float f32x4;
typedef __attribute__((ext_vector_type(8))) short bf16x8;
typedef __attribute__((ext_vector_type(8))) unsigned short u16x8;

// ---- workspace layout (bytes) ----
static const size_t OFF_BF    = 0;                 // 147456 (B fragments)
static const size_t OFF_T3    = 147456;            // 64 f32
static const size_t OFF_GLR   = 147712;            // [N][16] f32, 6.4 MB
static const size_t OFF_PB    = 6547712;           // [N][56] bf16
static const size_t OFF_LQ    = 17747712;          // [N][56] bf16
static const size_t OFF_DENOM = 28947712;          // [N] f32
static const size_t OFF_NUMER = 29347712;          // [N] f32
static const size_t OFF_LLP   = 29747712;          // [NB_FUSED] f32
static const size_t OFF_CEP   = 29748736;          // [NB_CE] f32
static const size_t OFF_XF    = 29751296;          // [NRB][16][64][8] bf16 = 102.4 MB
static const size_t ZERO_BEG  = OFF_DENOM;
static const size_t ZERO_BYTES= 29747712 - 28947712;

__device__ __forceinline__ ushort f2bf(float f) {
    union { float f; unsigned u; } v; v.f = f;
    unsigned r = v.u + 0x7fffu + ((v.u >> 16) & 1u);
    return (ushort)(r >> 16);
}
__device__ __forceinline__ float bf2f(ushort b) {
    union { unsigned u; float f; } v; v.u = ((unsigned)b) << 16; return v.f;
}
__device__ __forceinline__ float u2f(unsigned u) {
    union { unsigned u; float f; } v; v.u = u; return v.f;
}
__device__ __forceinline__ unsigned cvt_pk_bf16(float lo, float hi) {
    unsigned r;
    asm("v_cvt_pk_bf16_f32 %0, %1, %2" : "=v"(r) : "v"(lo), "v"(hi));
    return r;
}
__device__ __forceinline__ void gload16(const void* g, void* l) {
    __builtin_amdgcn_global_load_lds(
        (const __attribute__((address_space(1))) unsigned int*)g,
        (__attribute__((address_space(3))) unsigned int*)l,
        16, 0, 0);
}

// ---------- prep: B fragments (blocks < 288) + t3 (blocks 288..300) ----------
__global__ __launch_bounds__(256) void k_prep(const float* __restrict__ Var,
                                              const float* __restrict__ Mu,
                                              const float* __restrict__ wl,
                                              const float* __restrict__ wr,
                                              ushort* __restrict__ Bf,
                                              float* __restrict__ t3) {
    if (blockIdx.x < 288) {
        int id = blockIdx.x * 256 + threadIdx.x;
        int e    = id & 7;
        int lane = (id >> 3) & 63;
        int jk   = id >> 9;
        int kt   = jk / 18;
        int j    = jk - kt * 18;
        float v = 0.f;
        if (j < 16) {
            int t  = j >> 1, ss = j & 1;
            int s  = kt * 2 + ss;
            int k  = s * 32 + ((lane >> 4) << 3) + e;
            int c  = (t & 3) * 16 + (lane & 15);
            if (k < N_GENES && c < N_CLASSES)
                v = (t < 4) ? 1.0f / Var[c * N_GENES + k]
                            : Mu[c * N_GENES + k] / Var[c * N_GENES + k];
        } else {
            int ss = j - 16;
            int s  = kt * 2 + ss;
            int k  = s * 32 + ((lane >> 4) << 3) + e;
            int h  = lane & 15;
            if (k < N_GENES)
                v = (h < HID) ? wl[h * N_GENES + k] : wr[(h - HID) * N_GENES + k];
        }
        Bf[id] = f2bf(v);
    } else {
        int c = (blockIdx.x - 288) * 4 + (threadIdx.x >> 6);
        int lane = threadIdx.x & 63;
        if (c >= N_CLASSES) return;
        float s = 0.f;
        for (int g = lane; g < N_GENES; g += 64) {
            float m = Mu[c * N_GENES + g];
            s += m * m / Var[c * N_GENES + g];
        }
        #pragma unroll
        for (int off = 32; off; off >>= 1) s += __shfl_xor(s, off);
        if (lane == 0) t3[c] = s;
    }
}

// ---------- convert X -> bf16 fragment layout (blocks < NRB) + softmax ----------
__global__ __launch_bounds__(256) void k_cvt_sm(const float* __restrict__ X,
                                                ushort* __restrict__ Xf,
                                                const float* __restrict__ W,
                                                float* __restrict__ P,
                                                ushort* __restrict__ Pb,
                                                ushort* __restrict__ LQ) {
    if (blockIdx.x < NRB) {
        __shared__ float lx[16][516];   // stride 516 breaks bank alignment
        int tid = threadIdx.x, lane = tid & 63, wv = tid >> 6;
        int rb = blockIdx.x;
        const float* Xb = X + (size_t)rb * 16 * N_GENES;
        #pragma unroll
        for (int rr = 0; rr < 4; ++rr) {
            int row = wv * 4 + rr;
            const f32x4* src = (const f32x4*)(Xb + (size_t)row * N_GENES);
            f32x4 v0 = src[lane];
            *(f32x4*)&lx[row][lane * 4] = v0;
            if (lane < 61) {
                f32x4 v1 = src[64 + lane];
                *(f32x4*)&lx[row][256 + lane * 4] = v1;
            }
            if (lane < 12) lx[row][500 + lane] = 0.f;
        }
        __syncthreads();
        int s = tid >> 4, lgrp = tid & 15;
        unsigned outw[16];
        #pragma unroll
        for (int q = 0; q < 4; ++q) {
            int lane2 = lgrp * 4 + q;
            int row = lane2 & 15, kg = lane2 >> 4;
            int k0 = s * 32 + kg * 8;
            f32x4 p0 = *(const f32x4*)&lx[row][k0];
            f32x4 p1 = *(const f32x4*)&lx[row][k0 + 4];
            outw[q * 4 + 0] = cvt_pk_bf16(p0[0], p0[1]);
            outw[q * 4 + 1] = cvt_pk_bf16(p0[2], p0[3]);
            outw[q * 4 + 2] = cvt_pk_bf16(p1[0], p1[1]);
            outw[q * 4 + 3] = cvt_pk_bf16(p1[2], p1[3]);
        }
        uint4* dst = (uint4*)(Xf + (size_t)rb * 8192 + (size_t)tid * 32);
        #pragma unroll
        for (int q = 0; q < 4; ++q)
            dst[q] = make_uint4(outw[q*4], outw[q*4+1], outw[q*4+2], outw[q*4+3]);
    } else {
        int wid  = (blockIdx.x - NRB) * 4 + (threadIdx.x >> 6);
        int lane = threadIdx.x & 63;
        if (wid >= N_CELLS) return;
        float w = (lane < N_CLASSES) ? W[(size_t)wid * N_CLASSES + lane] : -__builtin_inff();
        float m = w;
        #pragma unroll
        for (int off = 32; off; off >>= 1) m = fmaxf(m, __shfl_xor(m, off));
        float e = (lane < N_CLASSES) ? expf(w - m) : 0.f;
        float s = e;
        #pragma unroll
        for (int off = 32; off; off >>= 1) s += __shfl_xor(s, off);
        float p = e / s;
        if (lane < N_CLASSES) P[(size_t)wid * N_CLASSES + lane] = p;
        if (lane < PROWS) {
            Pb[(size_t)wid * PROWS + lane] = (lane < N_CLASSES) ? f2bf(p) : 0;
            LQ[(size_t)wid * PROWS + lane] = (lane < N_CLASSES) ? f2bf(logf(p + 1e-8f)) : 0;
        }
    }
}

// ---------- fused MFMA: persistent-B in LDS, LINEAR bf16-fragment A loads ----------
__global__ __launch_bounds__(1024, 4) void k_fused(const ushort* __restrict__ Xf,
                                                   const float* __restrict__ S,
                                                   const float* __restrict__ P,
                                                   const ushort* __restrict__ Bf,
                                                   const float* __restrict__ t3,
                                                   const float* __restrict__ bl,
                                                   const float* __restrict__ br,
                                                   float* __restrict__ glr,
                                                   float* __restrict__ llp) {
    __shared__ ushort ldsB[73728];   // 147456 B
    __shared__ float  wsum[16];
    int tid  = threadIdx.x;
    int lane = tid & 63;
    int wv   = tid >> 6;
    int slot = lane & 15;
    const char* Bfc = (const char*)Bf;

    #pragma unroll
    for (int i = 0; i < 9; ++i) {
        size_t off = (size_t)(i * 16 + wv) * 1024;
        gload16(Bfc + off + (size_t)lane * 16, ((char*)ldsB) + off);
    }
    asm volatile("s_waitcnt vmcnt(0)" ::: "memory");
    __syncthreads();
    const bf16x8* BL  = (const bf16x8*)ldsB;
    const bf16x8* Xf8 = (const bf16x8*)Xf;

    int col = slot;
    int rg  = lane >> 4;
    float bias = (col < HID) ? bl[col] : br[col - HID];
    float llacc = 0.f;

    for (int g = blockIdx.x * 16 + wv; g < NRB; g += 4096) {
        int rbase = g * 16;
        float m2s = -2.0f * S[rbase + slot];
        const bf16x8* xg = Xf8 + (size_t)g * 1024 + lane;

        const f32x4 zz = {0.f, 0.f, 0.f, 0.f};
        f32x4 acc1[4], acc2[4], acc3;
        #pragma unroll
        for (int ct = 0; ct < 4; ++ct) { acc1[ct] = zz; acc2[ct] = zz; }
        acc3 = zz;

        #pragma unroll
        for (int kt = 0; kt < NKT; ++kt) {
            union { bf16x8 v; unsigned u[4]; } xlo, xhi;
            xlo.v = xg[(size_t)(kt * 2) * 64];       // linear 1-KB wave load
            xhi.v = xg[(size_t)(kt * 2 + 1) * 64];   // linear 1-KB wave load
            int j0 = kt * 18;
            #pragma unroll
            for (int ks = 0; ks < 2; ++ks) {
                const unsigned* xu = ks ? xhi.u : xlo.u;
                union { bf16x8 v; unsigned u[4]; } a1, a2;
                #pragma unroll
                for (int h = 0; h < 4; ++h) {
                    float fe = u2f(xu[h] << 16);
                    float fo = u2f(xu[h] & 0xffff0000u);
                    a1.u[h] = cvt_pk_bf16(fe * fe, fo * fo);
                    a2.u[h] = cvt_pk_bf16(m2s * fe, m2s * fo);
                }
                #pragma unroll
                for (int ct = 0; ct < 4; ++ct)
                    acc1[ct] = __builtin_amdgcn_mfma_f32_16x16x32_bf16(
                        a1.v, BL[(j0 + ct * 2 + ks) * 64 + lane], acc1[ct], 0, 0, 0);
                #pragma unroll
                for (int ct = 0; ct < 4; ++ct)
                    acc2[ct] = __builtin_amdgcn_mfma_f32_16x16x32_bf16(
                        a2.v, BL[(j0 + (4 + ct) * 2 + ks) * 64 + lane], acc2[ct], 0, 0, 0);
                acc3 = __builtin_amdgcn_mfma_f32_16x16x32_bf16(
                    a2.v, BL[(j0 + 16 + ks) * 64 + lane], acc3, 0, 0, 0);
            }
        }

        float part = 0.f;
        #pragma unroll
        for (int r = 0; r < 4; ++r) {
            int row = rbase + rg * 4 + r;
            float s2 = S[row];
            glr[(size_t)row * 16 + col] = acc3[r] / (-2.0f * s2) + bias;
            float ss = s2 * s2;
            #pragma unroll
            for (int ct = 0; ct < 4; ++ct) {
                int c = ct * 16 + col;
                if (c < N_CLASSES) {
                    float F = -0.5f * (acc1[ct][r] + acc2[ct][r] + ss * t3[c]);
                    part = fmaf(P[(size_t)row * N_CLASSES + c], F, part);
                }
            }
        }
        #pragma unroll
        for (int off = 32; off; off >>= 1) part += __shfl_xor(part, off);
        llacc += part;
    }

    __syncthreads();
    if (lane == 0) wsum[wv] = llacc;
    __syncthreads();
    if (tid == 0) {
        float s = 0.f;
        #pragma unroll
        for (int i = 0; i < 16; ++i) s += wsum[i];
        llp[blockIdx.x] = s;
    }
}

// ---------- fused edge pass ----------
__global__ __launch_bounds__(256) void k_edge(const int* __restrict__ ei,
                                              const float* __restrict__ glr,
                                              const float* __restrict__ att,
                                              const ushort* __restrict__ Pb,
                                              const ushort* __restrict__ LQ,
                                              float* __restrict__ denom,
                                              float* __restrict__ numer) {
    int e = blockIdx.x * 256 + threadIdx.x;
    if (e >= N_EDGES) return;
    int src = ei[e], dst = ei[N_EDGES + e];
    const float4* a = (const float4*)(glr + (size_t)src * 16);
    const float4* b = (const float4*)(glr + (size_t)dst * 16 + 8);
    float4 g0 = a[0], g1 = a[1], h0 = b[0], h1 = b[1];
    const float4* at = (const float4*)att;
    float4 a0 = at[0], a1 = at[1];
    float t, s = 0.f;
    t = g0.x + h0.x; t = t > 0.f ? t : 0.2f * t; s = fmaf(a0.x, t, s);
    t = g0.y + h0.y; t = t > 0.f ? t : 0.2f * t; s = fmaf(a0.y, t, s);
    t = g0.z + h0.z; t = t > 0.f ? t : 0.2f * t; s = fmaf(a0.z, t, s);
    t = g0.w + h0.w; t = t > 0.f ? t : 0.2f * t; s = fmaf(a0.w, t, s);
    t = g1.x + h1.x; t = t > 0.f ? t : 0.2f * t; s = fmaf(a1.x, t, s);
    t = g1.y + h1.y; t = t > 0.f ? t : 0.2f * t; s = fmaf(a1.y, t, s);
    t = g1.z + h1.z; t = t > 0.f ? t : 0.2f * t; s = fmaf(a1.z, t, s);
    t = g1.w + h1.w; t = t > 0.f ? t : 0.2f * t; s = fmaf(a1.w, t, s);
    float ex = expf(s);

    const u16x8* ps = (const u16x8*)(Pb + (size_t)src * PROWS);
    const u16x8* ld = (const u16x8*)(LQ + (size_t)dst * PROWS);
    float v = 0.f;
    #pragma unroll
    for (int i = 0; i < 7; ++i) {
        u16x8 pv = ps[i], lv = ld[i];
        #pragma unroll
        for (int j = 0; j < 8; ++j)
            v = fmaf(bf2f(pv[j]), bf2f(lv[j]), v);
    }
    atomicAdd(denom + dst, ex);
    atomicAdd(numer + dst, ex * v);
}

// ---------- CE node reduce ----------
__global__ __launch_bounds__(256) void k_ce(const float* __restrict__ denom,
                                            const float* __restrict__ numer,
                                            float* __restrict__ cep) {
    __shared__ float wsum[4];
    int n = blockIdx.x * 256 + threadIdx.x;
    float v = 0.f;
    if (n < N_CELLS) {
        float d = denom[n];
        v = (d > 0.f) ? numer[n] / d : 0.f;
    }
    #pragma unroll
    for (int off = 32; off; off >>= 1) v += __shfl_xor(v, off);
    if ((threadIdx.x & 63) == 0) wsum[threadIdx.x >> 6] = v;
    __syncthreads();
    if (threadIdx.x == 0) cep[blockIdx.x] = wsum[0] + wsum[1] + wsum[2] + wsum[3];
}

// ---------- final reduce ----------
__global__ __launch_bounds__(256) void k_reduce(const float* __restrict__ llp,
                                                const float* __restrict__ cep,
                                                float* __restrict__ out) {
    __shared__ double l1[256], l2[256];
    int t = threadIdx.x;
    double s1 = 0.0, s2 = 0.0;
    for (int i = t; i < NB_FUSED; i += 256) s1 += (double)llp[i];
    for (int i = t; i < NB_CE; i += 256) s2 += (double)cep[i];
    l1[t] = s1; l2[t] = s2;
    __syncthreads();
    for (int off = 128; off; off >>= 1) {
        if (t < off) { l1[t] += l1[t + off]; l2[t] += l2[t + off]; }
        __syncthreads();
    }
    if (t == 0) {
        out[0] = (float)(l1[0] / (double)N_CELLS);
        out[1] = (float)(-l2[0] / (double)N_CELLS);
    }
}

extern "C" void kernel_launch(void* const* d_in, const int* in_sizes, int n_in,
                              void* d_out, int out_size, void* d_ws, size_t ws_size,
                              hipStream_t stream) {
    const float* X   = (const float*)d_in[0];
    const float* Mu  = (const float*)d_in[1];
    const float* Var = (const float*)d_in[2];
    const float* W   = (const float*)d_in[3];
    const float* S   = (const float*)d_in[4];
    const int*   ei  = (const int*)d_in[5];
    const float* wl  = (const float*)d_in[6];
    const float* bl  = (const float*)d_in[7];
    const float* wr  = (const float*)d_in[8];
    const float* br  = (const float*)d_in[9];
    const float* att = (const float*)d_in[10];
    float* out = (float*)d_out;
    char*  ws  = (char*)d_ws;

    ushort* Bf    = (ushort*)(ws + OFF_BF);
    float*  t3    = (float*)(ws + OFF_T3);
    float*  glr   = (float*)(ws + OFF_GLR);
    ushort* Pb    = (ushort*)(ws + OFF_PB);
    ushort* LQ    = (ushort*)(ws + OFF_LQ);
    float*  denom = (float*)(ws + OFF_DENOM);
    float*  numer = (float*)(ws + OFF_NUMER);
    float*  llp   = (float*)(ws + OFF_LLP);
    float*  cep   = (float*)(ws + OFF_CEP);
    ushort* Xf    = (ushort*)(ws + OFF_XF);
    float*  P     = out + 2;

    hipMemsetAsync(ws + ZERO_BEG, 0, ZERO_BYTES, stream);

    k_prep   <<<301, 256, 0, stream>>>(Var, Mu, wl, wr, Bf, t3);
    k_cvt_sm <<<NRB + 25000, 256, 0, stream>>>(X, Xf, W, P, Pb, LQ);
    k_fused  <<<NB_FUSED, 1024, 0, stream>>>(Xf, S, P, Bf, t3, bl, br, glr, llp);
    k_edge   <<<(N_EDGES + 255) / 256, 256, 0, stream>>>(ei, glr, att, Pb, LQ, denom, numer);
    k_ce     <<<NB_CE, 256, 0, stream>>>(denom, numer, cep);
    k_reduce <<<1, 256, 0, stream>>>(llp, cep, out);
}

// Round 11
// 189.797 us; speedup vs baseline: 1.5307x; 1.5307x over previous
//
#include <hip/hip_runtime.h>
#include <math.h>

#define N_CELLS   100000
#define N_CLASSES 50
#define N_GENES   500
#define N_EDGES   600000
#define HID       8
#define NKT       8    // K tiles of 64 floats (512 padded)
#define NB_FUSED  1563 // ceil(N_CELLS/64)
#define NB_CE     391  // (N_CELLS+255)/256
#define PROWS     56   // padded bf16 P/LQ row length

typedef __attribute__((ext_vector_type(4))) float f32x4;
typedef __attribute__((ext_vector_type(8))) short bf16x8;
typedef __attribute__((ext_vector_type(8))) unsigned short u16x8;

// ---- workspace layout (bytes) ----
// Bf: [8 kt][18 j][64 lane][8 bf16] = 147456 B (j 0..15 class tiles, 16..17 glr)
static const size_t OFF_BF    = 0;                 // 147456
static const size_t OFF_T3    = 147456;            // 64 f32
static const size_t OFF_GLR   = 147712;            // [N][16] f32, 6.4 MB
static const size_t OFF_PB    = 6547712;           // [N][56] bf16, 11.2 MB
static const size_t OFF_LQ    = 17747712;          // [N][56] bf16, 11.2 MB
static const size_t OFF_DENOM = 28947712;          // [N] f32
static const size_t OFF_NUMER = 29347712;          // [N] f32
static const size_t OFF_LLP   = 29747712;          // [NB_FUSED] f32
static const size_t OFF_CEP   = 29754112;          // [NB_CE] f32
static const size_t ZERO_BEG  = OFF_DENOM;
static const size_t ZERO_BYTES= 29747712 - 28947712;   // denom+numer, 800 KB

__device__ __forceinline__ ushort f2bf(float f) {
    union { float f; unsigned u; } v; v.f = f;
    unsigned r = v.u + 0x7fffu + ((v.u >> 16) & 1u);   // RNE
    return (ushort)(r >> 16);
}
__device__ __forceinline__ float bf2f(ushort b) {
    union { unsigned u; float f; } v; v.u = ((unsigned)b) << 16; return v.f;
}
__device__ __forceinline__ unsigned cvt_pk_bf16(float lo, float hi) {
    unsigned r;
    asm("v_cvt_pk_bf16_f32 %0, %1, %2" : "=v"(r) : "v"(lo), "v"(hi));
    return r;
}
__device__ __forceinline__ void gload16(const void* g, void* l) {
    __builtin_amdgcn_global_load_lds(
        (const __attribute__((address_space(1))) unsigned int*)g,
        (__attribute__((address_space(3))) unsigned int*)l,
        16, 0, 0);
}

// ---------- prep: B fragments, k-tile-major for LDS staging (R7 layout) ----------
// main region [kt][j 0..15][lane][e]; glr region at 131072 [kt*2+ss][lane][e]
__global__ __launch_bounds__(256) void k_prepB(const float* __restrict__ Var,
                                               const float* __restrict__ Mu,
                                               const float* __restrict__ wl,
                                               const float* __restrict__ wr,
                                               ushort* __restrict__ Bf) {
    int id = blockIdx.x * 256 + threadIdx.x;           // 0..73727 exact
    float v = 0.f;
    if (id < 65536) {
        int e    = id & 7;
        int lane = (id >> 3) & 63;
        int j    = (id >> 9) & 15;
        int kt   = id >> 13;
        int t    = j >> 1, ss = j & 1;
        int s    = kt * 2 + ss;
        int k    = s * 32 + ((lane >> 4) << 3) + e;
        int c    = (t & 3) * 16 + (lane & 15);
        if (k < N_GENES && c < N_CLASSES)
            v = (t < 4) ? 1.0f / Var[c * N_GENES + k]
                        : Mu[c * N_GENES + k] / Var[c * N_GENES + k];
    } else {
        int rem  = id - 65536;
        int e    = rem & 7;
        int lane = (rem >> 3) & 63;
        int s    = rem >> 9;              // 0..15
        int k    = s * 32 + ((lane >> 4) << 3) + e;
        int h    = lane & 15;
        if (k < N_GENES)
            v = (h < HID) ? wl[h * N_GENES + k] : wr[(h - HID) * N_GENES + k];
    }
    Bf[id] = f2bf(v);
}

// ---------- t3 ----------
__global__ void k_t3(const float* __restrict__ Var, const float* __restrict__ Mu,
                     float* __restrict__ t3) {
    int c = blockIdx.x;
    int lane = threadIdx.x;
    float s = 0.f;
    for (int g = lane; g < N_GENES; g += 64) {
        float m = Mu[c * N_GENES + g];
        s += m * m / Var[c * N_GENES + g];
    }
    #pragma unroll
    for (int off = 32; off; off >>= 1) s += __shfl_xor(s, off);
    if (lane == 0) t3[c] = s;
}

// ---------- row softmax: P f32 + bf16 P + bf16 log(P+eps) ----------
__global__ __launch_bounds__(256) void k_softmax(const float* __restrict__ W,
                                                 float* __restrict__ P,
                                                 ushort* __restrict__ Pb,
                                                 ushort* __restrict__ LQ) {
    int wid  = (blockIdx.x * 256 + threadIdx.x) >> 6;
    int lane = threadIdx.x & 63;
    if (wid >= N_CELLS) return;
    float w = (lane < N_CLASSES) ? W[(size_t)wid * N_CLASSES + lane] : -__builtin_inff();
    float m = w;
    #pragma unroll
    for (int off = 32; off; off >>= 1) m = fmaxf(m, __shfl_xor(m, off));
    float e = (lane < N_CLASSES) ? expf(w - m) : 0.f;
    float s = e;
    #pragma unroll
    for (int off = 32; off; off >>= 1) s += __shfl_xor(s, off);
    float p = e / s;
    if (lane < N_CLASSES) P[(size_t)wid * N_CLASSES + lane] = p;
    if (lane < PROWS) {
        Pb[(size_t)wid * PROWS + lane] = (lane < N_CLASSES) ? f2bf(p) : 0;
        LQ[(size_t)wid * PROWS + lane] = (lane < N_CLASSES) ? f2bf(logf(p + 1e-8f)) : 0;
    }
}

// ---------- fused MFMA (R7 verbatim): dbuf A+B LDS, counted vmcnt(9) ----------
__global__ __launch_bounds__(256, 2) void k_fused(const float* __restrict__ X,
                                                  const float* __restrict__ S,
                                                  const float* __restrict__ P,
                                                  const ushort* __restrict__ Bf,
                                                  const float* __restrict__ t3,
                                                  const float* __restrict__ bl,
                                                  const float* __restrict__ br,
                                                  float* __restrict__ glr,
                                                  float* __restrict__ llp) {
    __shared__ float  ldsA[2][4][16][16][4];   // 32 KB
    __shared__ ushort ldsB[2][20][64][8];      // 40 KB (18 real + 2 pad)
    __shared__ float  wsum[4];
    int tid  = threadIdx.x;
    int lane = tid & 63;
    int wv   = tid >> 6;
    int lhi  = lane >> 4;
    int slot = lane & 15;
    int rbase = blockIdx.x * 64 + wv * 16;
    const char* Xc  = (const char*)X;
    const char* Bfc = (const char*)Bf;

    int arow = rbase + slot;
    if (arow > N_CELLS - 1) arow = N_CELLS - 1;
    float m2s = -2.0f * S[arow];

    const f32x4 zz = {0.f, 0.f, 0.f, 0.f};
    f32x4 acc1[4], acc2[4], acc3;
    #pragma unroll
    for (int ct = 0; ct < 4; ++ct) { acc1[ct] = zz; acc2[ct] = zz; }
    acc3 = zz;

#define STAGE(KT, BUF) do {                                                        \
    _Pragma("unroll")                                                              \
    for (int i = 0; i < 4; ++i) {                                                  \
        int rloc = i * 4 + lhi;                                                    \
        int row  = rbase + rloc; if (row > N_CELLS - 1) row = N_CELLS - 1;         \
        int gi   = (KT) * 16 + (slot ^ (rloc & 7)); if (gi > 124) gi = 124;        \
        gload16(Xc + (size_t)row * 2000 + (size_t)gi * 16, &ldsA[BUF][wv][i * 4][0][0]); \
    }                                                                              \
    _Pragma("unroll")                                                              \
    for (int i = 0; i < 5; ++i) {                                                  \
        int j = wv * 5 + i;                                                        \
        size_t src;                                                                \
        if (j < 16)      src = (size_t)(KT) * 16384 + (size_t)j * 1024;            \
        else if (j < 18) src = 131072 + ((size_t)(KT) * 2 + (size_t)(j - 16)) * 1024; \
        else             src = (size_t)(KT) * 16384;                               \
        gload16(Bfc + src + (size_t)lane * 16, &ldsB[BUF][j][0][0]);               \
    }                                                                              \
} while (0)

    STAGE(0, 0);

    #pragma unroll
    for (int kt = 0; kt < NKT; ++kt) {
        const int cur = kt & 1;
        if (kt < NKT - 1) {
            STAGE(kt + 1, cur ^ 1);
            __builtin_amdgcn_sched_barrier(0);
            asm volatile("s_waitcnt vmcnt(9)" ::: "memory");
        } else {
            __builtin_amdgcn_sched_barrier(0);
            asm volatile("s_waitcnt vmcnt(0)" ::: "memory");
        }
        __builtin_amdgcn_sched_barrier(0);
        __builtin_amdgcn_s_barrier();
        __builtin_amdgcn_sched_barrier(0);

        const bf16x8* BL = (const bf16x8*)&ldsB[cur][0][0][0];
        #pragma unroll
        for (int ks = 0; ks < 2; ++ks) {
            int key = slot & 7;
            int c0  = ks * 8 + lhi * 2;
            f32x4 xa = *(const f32x4*)&ldsA[cur][wv][slot][c0 ^ key][0];
            f32x4 xb = *(const f32x4*)&ldsA[cur][wv][slot][(c0 + 1) ^ key][0];
            union { bf16x8 v; unsigned u[4]; } a1, a2;
            a1.u[0] = cvt_pk_bf16(xa[0] * xa[0], xa[1] * xa[1]);
            a1.u[1] = cvt_pk_bf16(xa[2] * xa[2], xa[3] * xa[3]);
            a1.u[2] = cvt_pk_bf16(xb[0] * xb[0], xb[1] * xb[1]);
            a1.u[3] = cvt_pk_bf16(xb[2] * xb[2], xb[3] * xb[3]);
            a2.u[0] = cvt_pk_bf16(m2s * xa[0], m2s * xa[1]);
            a2.u[1] = cvt_pk_bf16(m2s * xa[2], m2s * xa[3]);
            a2.u[2] = cvt_pk_bf16(m2s * xb[0], m2s * xb[1]);
            a2.u[3] = cvt_pk_bf16(m2s * xb[2], m2s * xb[3]);
            bf16x8 bg = BL[(16 + ks) * 64 + lane];
            #pragma unroll
            for (int ct = 0; ct < 4; ++ct)
                acc1[ct] = __builtin_amdgcn_mfma_f32_16x16x32_bf16(a1.v, BL[(ct * 2 + ks) * 64 + lane], acc1[ct], 0, 0, 0);
            #pragma unroll
            for (int ct = 0; ct < 4; ++ct)
                acc2[ct] = __builtin_amdgcn_mfma_f32_16x16x32_bf16(a2.v, BL[((4 + ct) * 2 + ks) * 64 + lane], acc2[ct], 0, 0, 0);
            acc3 = __builtin_amdgcn_mfma_f32_16x16x32_bf16(a2.v, bg, acc3, 0, 0, 0);
        }
        __builtin_amdgcn_sched_barrier(0);
        __builtin_amdgcn_s_barrier();
        __builtin_amdgcn_sched_barrier(0);
    }
#undef STAGE

    int col = lane & 15;
    int rg  = lane >> 4;
    float bias = (col < HID) ? bl[col] : br[col - HID];
    float part = 0.f;
    #pragma unroll
    for (int r = 0; r < 4; ++r) {
        int row = rbase + rg * 4 + r;
        if (row < N_CELLS) {
            float s2 = S[row];
            glr[(size_t)row * 16 + col] = acc3[r] / (-2.0f * s2) + bias;
            float ss = s2 * s2;
            #pragma unroll
            for (int ct = 0; ct < 4; ++ct) {
                int c = ct * 16 + col;
                if (c < N_CLASSES) {
                    float F = -0.5f * (acc1[ct][r] + acc2[ct][r] + ss * t3[c]);
                    part = fmaf(P[(size_t)row * N_CLASSES + c], F, part);
                }
            }
        }
    }
    #pragma unroll
    for (int off = 32; off; off >>= 1) part += __shfl_xor(part, off);
    if (lane == 0) wsum[wv] = part;
    __syncthreads();
    if (tid == 0) llp[blockIdx.x] = wsum[0] + wsum[1] + wsum[2] + wsum[3];
}

// ---------- fused edge pass: score + exp + CE dot, no segment max (R8) ----------
__global__ __launch_bounds__(256) void k_edge(const int* __restrict__ ei,
                                              const float* __restrict__ glr,
                                              const float* __restrict__ att,
                                              const ushort* __restrict__ Pb,
                                              const ushort* __restrict__ LQ,
                                              float* __restrict__ denom,
                                              float* __restrict__ numer) {
    int e = blockIdx.x * 256 + threadIdx.x;
    if (e >= N_EDGES) return;
    int src = ei[e], dst = ei[N_EDGES + e];
    const float4* a = (const float4*)(glr + (size_t)src * 16);
    const float4* b = (const float4*)(glr + (size_t)dst * 16 + 8);
    float4 g0 = a[0], g1 = a[1], h0 = b[0], h1 = b[1];
    const float4* at = (const float4*)att;
    float4 a0 = at[0], a1 = at[1];
    float t, s = 0.f;
    t = g0.x + h0.x; t = t > 0.f ? t : 0.2f * t; s = fmaf(a0.x, t, s);
    t = g0.y + h0.y; t = t > 0.f ? t : 0.2f * t; s = fmaf(a0.y, t, s);
    t = g0.z + h0.z; t = t > 0.f ? t : 0.2f * t; s = fmaf(a0.z, t, s);
    t = g0.w + h0.w; t = t > 0.f ? t : 0.2f * t; s = fmaf(a0.w, t, s);
    t = g1.x + h1.x; t = t > 0.f ? t : 0.2f * t; s = fmaf(a1.x, t, s);
    t = g1.y + h1.y; t = t > 0.f ? t : 0.2f * t; s = fmaf(a1.y, t, s);
    t = g1.z + h1.z; t = t > 0.f ? t : 0.2f * t; s = fmaf(a1.z, t, s);
    t = g1.w + h1.w; t = t > 0.f ? t : 0.2f * t; s = fmaf(a1.w, t, s);
    float ex = expf(s);

    const u16x8* ps = (const u16x8*)(Pb + (size_t)src * PROWS);
    const u16x8* ld = (const u16x8*)(LQ + (size_t)dst * PROWS);
    float v = 0.f;
    #pragma unroll
    for (int i = 0; i < 7; ++i) {
        u16x8 pv = ps[i], lv = ld[i];
        #pragma unroll
        for (int j = 0; j < 8; ++j)
            v = fmaf(bf2f(pv[j]), bf2f(lv[j]), v);
    }
    atomicAdd(denom + dst, ex);
    atomicAdd(numer + dst, ex * v);
}

// ---------- CE node reduce -> per-block partial ----------
__global__ __launch_bounds__(256) void k_ce(const float* __restrict__ denom,
                                            const float* __restrict__ numer,
                                            float* __restrict__ cep) {
    __shared__ float wsum[4];
    int n = blockIdx.x * 256 + threadIdx.x;
    float v = 0.f;
    if (n < N_CELLS) {
        float d = denom[n];
        v = (d > 0.f) ? numer[n] / d : 0.f;
    }
    #pragma unroll
    for (int off = 32; off; off >>= 1) v += __shfl_xor(v, off);
    if ((threadIdx.x & 63) == 0) wsum[threadIdx.x >> 6] = v;
    __syncthreads();
    if (threadIdx.x == 0) cep[blockIdx.x] = wsum[0] + wsum[1] + wsum[2] + wsum[3];
}

// ---------- final reduce ----------
__global__ __launch_bounds__(256) void k_reduce(const float* __restrict__ llp,
                                                const float* __restrict__ cep,
                                                float* __restrict__ out) {
    __shared__ double l1[256], l2[256];
    int t = threadIdx.x;
    double s1 = 0.0, s2 = 0.0;
    for (int i = t; i < NB_FUSED; i += 256) s1 += (double)llp[i];
    for (int i = t; i < NB_CE; i += 256) s2 += (double)cep[i];
    l1[t] = s1; l2[t] = s2;
    __syncthreads();
    for (int off = 128; off; off >>= 1) {
        if (t < off) { l1[t] += l1[t + off]; l2[t] += l2[t + off]; }
        __syncthreads();
    }
    if (t == 0) {
        out[0] = (float)(l1[0] / (double)N_CELLS);
        out[1] = (float)(-l2[0] / (double)N_CELLS);
    }
}

extern "C" void kernel_launch(void* const* d_in, const int* in_sizes, int n_in,
                              void* d_out, int out_size, void* d_ws, size_t ws_size,
                              hipStream_t stream) {
    const float* X   = (const float*)d_in[0];
    const float* Mu  = (const float*)d_in[1];
    const float* Var = (const float*)d_in[2];
    const float* W   = (const float*)d_in[3];
    const float* S   = (const float*)d_in[4];
    const int*   ei  = (const int*)d_in[5];
    const float* wl  = (const float*)d_in[6];
    const float* bl  = (const float*)d_in[7];
    const float* wr  = (const float*)d_in[8];
    const float* br  = (const float*)d_in[9];
    const float* att = (const float*)d_in[10];
    float* out = (float*)d_out;
    char*  ws  = (char*)d_ws;

    ushort* Bf    = (ushort*)(ws + OFF_BF);
    float*  t3    = (float*)(ws + OFF_T3);
    float*  glr   = (float*)(ws + OFF_GLR);
    ushort* Pb    = (ushort*)(ws + OFF_PB);
    ushort* LQ    = (ushort*)(ws + OFF_LQ);
    float*  denom = (float*)(ws + OFF_DENOM);
    float*  numer = (float*)(ws + OFF_NUMER);
    float*  llp   = (float*)(ws + OFF_LLP);
    float*  cep   = (float*)(ws + OFF_CEP);
    float*  P     = out + 2;

    hipMemsetAsync(ws + ZERO_BEG, 0, ZERO_BYTES, stream);

    k_prepB  <<<288, 256, 0, stream>>>(Var, Mu, wl, wr, Bf);
    k_t3     <<<N_CLASSES, 64, 0, stream>>>(Var, Mu, t3);
    k_softmax<<<(N_CELLS * 64 + 255) / 256, 256, 0, stream>>>(W, P, Pb, LQ);
    k_fused  <<<NB_FUSED, 256, 0, stream>>>(X, S, P, Bf, t3, bl, br, glr, llp);
    k_edge   <<<(N_EDGES + 255) / 256, 256, 0, stream>>>(ei, glr, att, Pb, LQ, denom, numer);
    k_ce     <<<NB_CE, 256, 0, stream>>>(denom, numer, cep);
    k_reduce <<<1, 256, 0, stream>>>(llp, cep, out);
}

// Round 12
// 179.086 us; speedup vs baseline: 1.6222x; 1.0598x over previous
//
#include <hip/hip_runtime.h>
#include <math.h>

#define N_CELLS   100000
#define N_CLASSES 50
#define N_GENES   500
#define N_EDGES   600000
#define HID       8
#define NKT       8    // K tiles of 64 floats (512 padded)
#define NB_FUSED  1563 // ceil(N_CELLS/64)
#define NB_CE     391  // (N_CELLS+255)/256
#define PROWS     56   // padded bf16 P/LQ row length

typedef __attribute__((ext_vector_type(4))) float f32x4;
typedef __attribute__((ext_vector_type(8))) short bf16x8;
typedef __attribute__((ext_vector_type(8))) unsigned short u16x8;

// ---- workspace layout (bytes) ----
// Bf: [8 kt][18 j][64 lane][8 bf16] = 147456 B (j 0..15 class tiles, 16..17 glr)
static const size_t OFF_BF    = 0;                 // 147456
static const size_t OFF_T3    = 147456;            // 64 f32
static const size_t OFF_GLR   = 147712;            // [N][16] bf16 now, 3.2 MB
static const size_t OFF_PB    = 6547712;           // [N][56] bf16, 11.2 MB
static const size_t OFF_LQ    = 17747712;          // [N][56] bf16, 11.2 MB
static const size_t OFF_DENOM = 28947712;          // [N] f32
static const size_t OFF_NUMER = 29347712;          // [N] f32
static const size_t OFF_LLP   = 29747712;          // [NB_FUSED] f32
static const size_t OFF_CEP   = 29754112;          // [NB_CE] f32
static const size_t ZERO_BEG  = OFF_DENOM;
static const size_t ZERO_BYTES= 29747712 - 28947712;   // denom+numer, 800 KB

__device__ __forceinline__ ushort f2bf(float f) {
    union { float f; unsigned u; } v; v.f = f;
    unsigned r = v.u + 0x7fffu + ((v.u >> 16) & 1u);   // RNE
    return (ushort)(r >> 16);
}
__device__ __forceinline__ float bf2f(ushort b) {
    union { unsigned u; float f; } v; v.u = ((unsigned)b) << 16; return v.f;
}
__device__ __forceinline__ unsigned cvt_pk_bf16(float lo, float hi) {
    unsigned r;
    asm("v_cvt_pk_bf16_f32 %0, %1, %2" : "=v"(r) : "v"(lo), "v"(hi));
    return r;
}
__device__ __forceinline__ void gload16(const void* g, void* l) {
    __builtin_amdgcn_global_load_lds(
        (const __attribute__((address_space(1))) unsigned int*)g,
        (__attribute__((address_space(3))) unsigned int*)l,
        16, 0, 0);
}

// ---------- prep: B fragments (blocks <288, R7 layout) + t3 (blocks 288+) ----------
__global__ __launch_bounds__(256) void k_prep(const float* __restrict__ Var,
                                              const float* __restrict__ Mu,
                                              const float* __restrict__ wl,
                                              const float* __restrict__ wr,
                                              ushort* __restrict__ Bf,
                                              float* __restrict__ t3) {
    if (blockIdx.x < 288) {
        int id = blockIdx.x * 256 + threadIdx.x;           // 0..73727 exact
        float v = 0.f;
        if (id < 65536) {
            int e    = id & 7;
            int lane = (id >> 3) & 63;
            int j    = (id >> 9) & 15;
            int kt   = id >> 13;
            int t    = j >> 1, ss = j & 1;
            int s    = kt * 2 + ss;
            int k    = s * 32 + ((lane >> 4) << 3) + e;
            int c    = (t & 3) * 16 + (lane & 15);
            if (k < N_GENES && c < N_CLASSES)
                v = (t < 4) ? 1.0f / Var[c * N_GENES + k]
                            : Mu[c * N_GENES + k] / Var[c * N_GENES + k];
        } else {
            int rem  = id - 65536;
            int e    = rem & 7;
            int lane = (rem >> 3) & 63;
            int s    = rem >> 9;              // 0..15
            int k    = s * 32 + ((lane >> 4) << 3) + e;
            int h    = lane & 15;
            if (k < N_GENES)
                v = (h < HID) ? wl[h * N_GENES + k] : wr[(h - HID) * N_GENES + k];
        }
        Bf[id] = f2bf(v);
    } else {
        int c    = (blockIdx.x - 288) * 4 + (threadIdx.x >> 6);
        int lane = threadIdx.x & 63;
        if (c >= N_CLASSES) return;
        float s = 0.f;
        for (int g = lane; g < N_GENES; g += 64) {
            float m = Mu[c * N_GENES + g];
            s += m * m / Var[c * N_GENES + g];
        }
        #pragma unroll
        for (int off = 32; off; off >>= 1) s += __shfl_xor(s, off);
        if (lane == 0) t3[c] = s;
    }
}

// ---------- row softmax: P f32 + bf16 P + bf16 log(P+eps) ----------
__global__ __launch_bounds__(256) void k_softmax(const float* __restrict__ W,
                                                 float* __restrict__ P,
                                                 ushort* __restrict__ Pb,
                                                 ushort* __restrict__ LQ) {
    int wid  = (blockIdx.x * 256 + threadIdx.x) >> 6;
    int lane = threadIdx.x & 63;
    if (wid >= N_CELLS) return;
    float w = (lane < N_CLASSES) ? W[(size_t)wid * N_CLASSES + lane] : -__builtin_inff();
    float m = w;
    #pragma unroll
    for (int off = 32; off; off >>= 1) m = fmaxf(m, __shfl_xor(m, off));
    float e = (lane < N_CLASSES) ? expf(w - m) : 0.f;
    float s = e;
    #pragma unroll
    for (int off = 32; off; off >>= 1) s += __shfl_xor(s, off);
    float p = e / s;
    if (lane < N_CLASSES) P[(size_t)wid * N_CLASSES + lane] = p;
    if (lane < PROWS) {
        Pb[(size_t)wid * PROWS + lane] = (lane < N_CLASSES) ? f2bf(p) : 0;
        LQ[(size_t)wid * PROWS + lane] = (lane < N_CLASSES) ? f2bf(logf(p + 1e-8f)) : 0;
    }
}

// ---------- fused MFMA (R7 verbatim, glr stored bf16) ----------
__global__ __launch_bounds__(256, 2) void k_fused(const float* __restrict__ X,
                                                  const float* __restrict__ S,
                                                  const float* __restrict__ P,
                                                  const ushort* __restrict__ Bf,
                                                  const float* __restrict__ t3,
                                                  const float* __restrict__ bl,
                                                  const float* __restrict__ br,
                                                  ushort* __restrict__ glrb,
                                                  float* __restrict__ llp) {
    __shared__ float  ldsA[2][4][16][16][4];   // 32 KB
    __shared__ ushort ldsB[2][20][64][8];      // 40 KB (18 real + 2 pad)
    __shared__ float  wsum[4];
    int tid  = threadIdx.x;
    int lane = tid & 63;
    int wv   = tid >> 6;
    int lhi  = lane >> 4;
    int slot = lane & 15;
    int rbase = blockIdx.x * 64 + wv * 16;
    const char* Xc  = (const char*)X;
    const char* Bfc = (const char*)Bf;

    int arow = rbase + slot;
    if (arow > N_CELLS - 1) arow = N_CELLS - 1;
    float m2s = -2.0f * S[arow];

    const f32x4 zz = {0.f, 0.f, 0.f, 0.f};
    f32x4 acc1[4], acc2[4], acc3;
    #pragma unroll
    for (int ct = 0; ct < 4; ++ct) { acc1[ct] = zz; acc2[ct] = zz; }
    acc3 = zz;

#define STAGE(KT, BUF) do {                                                        \
    _Pragma("unroll")                                                              \
    for (int i = 0; i < 4; ++i) {                                                  \
        int rloc = i * 4 + lhi;                                                    \
        int row  = rbase + rloc; if (row > N_CELLS - 1) row = N_CELLS - 1;         \
        int gi   = (KT) * 16 + (slot ^ (rloc & 7)); if (gi > 124) gi = 124;        \
        gload16(Xc + (size_t)row * 2000 + (size_t)gi * 16, &ldsA[BUF][wv][i * 4][0][0]); \
    }                                                                              \
    _Pragma("unroll")                                                              \
    for (int i = 0; i < 5; ++i) {                                                  \
        int j = wv * 5 + i;                                                        \
        size_t src;                                                                \
        if (j < 16)      src = (size_t)(KT) * 16384 + (size_t)j * 1024;            \
        else if (j < 18) src = 131072 + ((size_t)(KT) * 2 + (size_t)(j - 16)) * 1024; \
        else             src = (size_t)(KT) * 16384;                               \
        gload16(Bfc + src + (size_t)lane * 16, &ldsB[BUF][j][0][0]);               \
    }                                                                              \
} while (0)

    STAGE(0, 0);

    #pragma unroll
    for (int kt = 0; kt < NKT; ++kt) {
        const int cur = kt & 1;
        if (kt < NKT - 1) {
            STAGE(kt + 1, cur ^ 1);
            __builtin_amdgcn_sched_barrier(0);
            asm volatile("s_waitcnt vmcnt(9)" ::: "memory");
        } else {
            __builtin_amdgcn_sched_barrier(0);
            asm volatile("s_waitcnt vmcnt(0)" ::: "memory");
        }
        __builtin_amdgcn_sched_barrier(0);
        __builtin_amdgcn_s_barrier();
        __builtin_amdgcn_sched_barrier(0);

        const bf16x8* BL = (const bf16x8*)&ldsB[cur][0][0][0];
        #pragma unroll
        for (int ks = 0; ks < 2; ++ks) {
            int key = slot & 7;
            int c0  = ks * 8 + lhi * 2;
            f32x4 xa = *(const f32x4*)&ldsA[cur][wv][slot][c0 ^ key][0];
            f32x4 xb = *(const f32x4*)&ldsA[cur][wv][slot][(c0 + 1) ^ key][0];
            union { bf16x8 v; unsigned u[4]; } a1, a2;
            a1.u[0] = cvt_pk_bf16(xa[0] * xa[0], xa[1] * xa[1]);
            a1.u[1] = cvt_pk_bf16(xa[2] * xa[2], xa[3] * xa[3]);
            a1.u[2] = cvt_pk_bf16(xb[0] * xb[0], xb[1] * xb[1]);
            a1.u[3] = cvt_pk_bf16(xb[2] * xb[2], xb[3] * xb[3]);
            a2.u[0] = cvt_pk_bf16(m2s * xa[0], m2s * xa[1]);
            a2.u[1] = cvt_pk_bf16(m2s * xa[2], m2s * xa[3]);
            a2.u[2] = cvt_pk_bf16(m2s * xb[0], m2s * xb[1]);
            a2.u[3] = cvt_pk_bf16(m2s * xb[2], m2s * xb[3]);
            bf16x8 bg = BL[(16 + ks) * 64 + lane];
            #pragma unroll
            for (int ct = 0; ct < 4; ++ct)
                acc1[ct] = __builtin_amdgcn_mfma_f32_16x16x32_bf16(a1.v, BL[(ct * 2 + ks) * 64 + lane], acc1[ct], 0, 0, 0);
            #pragma unroll
            for (int ct = 0; ct < 4; ++ct)
                acc2[ct] = __builtin_amdgcn_mfma_f32_16x16x32_bf16(a2.v, BL[((4 + ct) * 2 + ks) * 64 + lane], acc2[ct], 0, 0, 0);
            acc3 = __builtin_amdgcn_mfma_f32_16x16x32_bf16(a2.v, bg, acc3, 0, 0, 0);
        }
        __builtin_amdgcn_sched_barrier(0);
        __builtin_amdgcn_s_barrier();
        __builtin_amdgcn_sched_barrier(0);
    }
#undef STAGE

    int col = lane & 15;
    int rg  = lane >> 4;
    float bias = (col < HID) ? bl[col] : br[col - HID];
    float part = 0.f;
    #pragma unroll
    for (int r = 0; r < 4; ++r) {
        int row = rbase + rg * 4 + r;
        if (row < N_CELLS) {
            float s2 = S[row];
            glrb[(size_t)row * 16 + col] = f2bf(acc3[r] / (-2.0f * s2) + bias);
            float ss = s2 * s2;
            #pragma unroll
            for (int ct = 0; ct < 4; ++ct) {
                int c = ct * 16 + col;
                if (c < N_CLASSES) {
                    float F = -0.5f * (acc1[ct][r] + acc2[ct][r] + ss * t3[c]);
                    part = fmaf(P[(size_t)row * N_CLASSES + c], F, part);
                }
            }
        }
    }
    #pragma unroll
    for (int off = 32; off; off >>= 1) part += __shfl_xor(part, off);
    if (lane == 0) wsum[wv] = part;
    __syncthreads();
    if (tid == 0) llp[blockIdx.x] = wsum[0] + wsum[1] + wsum[2] + wsum[3];
}

// ---------- fused edge pass: bf16 glr gathers (16 B each side) ----------
__global__ __launch_bounds__(256) void k_edge(const int* __restrict__ ei,
                                              const ushort* __restrict__ glrb,
                                              const float* __restrict__ att,
                                              const ushort* __restrict__ Pb,
                                              const ushort* __restrict__ LQ,
                                              float* __restrict__ denom,
                                              float* __restrict__ numer) {
    int e = blockIdx.x * 256 + threadIdx.x;
    if (e >= N_EDGES) return;
    int src = ei[e], dst = ei[N_EDGES + e];
    u16x8 gv = *(const u16x8*)(glrb + (size_t)src * 16);       // gl[0..7]
    u16x8 hv = *(const u16x8*)(glrb + (size_t)dst * 16 + 8);   // gr[0..7]
    const float4* at = (const float4*)att;
    float4 a0 = at[0], a1 = at[1];
    float t, s = 0.f;
    t = bf2f(gv[0]) + bf2f(hv[0]); t = t > 0.f ? t : 0.2f * t; s = fmaf(a0.x, t, s);
    t = bf2f(gv[1]) + bf2f(hv[1]); t = t > 0.f ? t : 0.2f * t; s = fmaf(a0.y, t, s);
    t = bf2f(gv[2]) + bf2f(hv[2]); t = t > 0.f ? t : 0.2f * t; s = fmaf(a0.z, t, s);
    t = bf2f(gv[3]) + bf2f(hv[3]); t = t > 0.f ? t : 0.2f * t; s = fmaf(a0.w, t, s);
    t = bf2f(gv[4]) + bf2f(hv[4]); t = t > 0.f ? t : 0.2f * t; s = fmaf(a1.x, t, s);
    t = bf2f(gv[5]) + bf2f(hv[5]); t = t > 0.f ? t : 0.2f * t; s = fmaf(a1.y, t, s);
    t = bf2f(gv[6]) + bf2f(hv[6]); t = t > 0.f ? t : 0.2f * t; s = fmaf(a1.z, t, s);
    t = bf2f(gv[7]) + bf2f(hv[7]); t = t > 0.f ? t : 0.2f * t; s = fmaf(a1.w, t, s);
    float ex = expf(s);

    const u16x8* ps = (const u16x8*)(Pb + (size_t)src * PROWS);
    const u16x8* ld = (const u16x8*)(LQ + (size_t)dst * PROWS);
    float v = 0.f;
    #pragma unroll
    for (int i = 0; i < 7; ++i) {
        u16x8 pv = ps[i], lv = ld[i];
        #pragma unroll
        for (int j = 0; j < 8; ++j)
            v = fmaf(bf2f(pv[j]), bf2f(lv[j]), v);
    }
    atomicAdd(denom + dst, ex);
    atomicAdd(numer + dst, ex * v);
}

// ---------- CE node reduce -> per-block partial ----------
__global__ __launch_bounds__(256) void k_ce(const float* __restrict__ denom,
                                            const float* __restrict__ numer,
                                            float* __restrict__ cep) {
    __shared__ float wsum[4];
    int n = blockIdx.x * 256 + threadIdx.x;
    float v = 0.f;
    if (n < N_CELLS) {
        float d = denom[n];
        v = (d > 0.f) ? numer[n] / d : 0.f;
    }
    #pragma unroll
    for (int off = 32; off; off >>= 1) v += __shfl_xor(v, off);
    if ((threadIdx.x & 63) == 0) wsum[threadIdx.x >> 6] = v;
    __syncthreads();
    if (threadIdx.x == 0) cep[blockIdx.x] = wsum[0] + wsum[1] + wsum[2] + wsum[3];
}

// ---------- final reduce ----------
__global__ __launch_bounds__(256) void k_reduce(const float* __restrict__ llp,
                                                const float* __restrict__ cep,
                                                float* __restrict__ out) {
    __shared__ double l1[256], l2[256];
    int t = threadIdx.x;
    double s1 = 0.0, s2 = 0.0;
    for (int i = t; i < NB_FUSED; i += 256) s1 += (double)llp[i];
    for (int i = t; i < NB_CE; i += 256) s2 += (double)cep[i];
    l1[t] = s1; l2[t] = s2;
    __syncthreads();
    for (int off = 128; off; off >>= 1) {
        if (t < off) { l1[t] += l1[t + off]; l2[t] += l2[t + off]; }
        __syncthreads();
    }
    if (t == 0) {
        out[0] = (float)(l1[0] / (double)N_CELLS);
        out[1] = (float)(-l2[0] / (double)N_CELLS);
    }
}

extern "C" void kernel_launch(void* const* d_in, const int* in_sizes, int n_in,
                              void* d_out, int out_size, void* d_ws, size_t ws_size,
                              hipStream_t stream) {
    const float* X   = (const float*)d_in[0];
    const float* Mu  = (const float*)d_in[1];
    const float* Var = (const float*)d_in[2];
    const float* W   = (const float*)d_in[3];
    const float* S   = (const float*)d_in[4];
    const int*   ei  = (const int*)d_in[5];
    const float* wl  = (const float*)d_in[6];
    const float* bl  = (const float*)d_in[7];
    const float* wr  = (const float*)d_in[8];
    const float* br  = (const float*)d_in[9];
    const float* att = (const float*)d_in[10];
    float* out = (float*)d_out;
    char*  ws  = (char*)d_ws;

    ushort* Bf    = (ushort*)(ws + OFF_BF);
    float*  t3    = (float*)(ws + OFF_T3);
    ushort* glrb  = (ushort*)(ws + OFF_GLR);
    ushort* Pb    = (ushort*)(ws + OFF_PB);
    ushort* LQ    = (ushort*)(ws + OFF_LQ);
    float*  denom = (float*)(ws + OFF_DENOM);
    float*  numer = (float*)(ws + OFF_NUMER);
    float*  llp   = (float*)(ws + OFF_LLP);
    float*  cep   = (float*)(ws + OFF_CEP);
    float*  P     = out + 2;

    hipMemsetAsync(ws + ZERO_BEG, 0, ZERO_BYTES, stream);

    k_prep   <<<301, 256, 0, stream>>>(Var, Mu, wl, wr, Bf, t3);
    k_softmax<<<(N_CELLS * 64 + 255) / 256, 256, 0, stream>>>(W, P, Pb, LQ);
    k_fused  <<<NB_FUSED, 256, 0, stream>>>(X, S, P, Bf, t3, bl, br, glrb, llp);
    k_edge   <<<(N_EDGES + 255) / 256, 256, 0, stream>>>(ei, glrb, att, Pb, LQ, denom, numer);
    k_ce     <<<NB_CE, 256, 0, stream>>>(denom, numer, cep);
    k_reduce <<<1, 256, 0, stream>>>(llp, cep, out);
}

// Round 13
// 175.018 us; speedup vs baseline: 1.6599x; 1.0232x over previous
//
#include <hip/hip_runtime.h>
#include <math.h>

#define N_CELLS   100000
#define N_CLASSES 50
#define N_GENES   500
#define N_EDGES   600000
#define HID       8
#define NKT       8    // K tiles of 64 floats (512 padded)
#define NB_FUSED  1563 // ceil(N_CELLS/64)
#define NB_CE     391  // (N_CELLS+255)/256
#define PROWS     56   // padded bf16 P/LQ row length

typedef __attribute__((ext_vector_type(4))) float f32x4;
typedef __attribute__((ext_vector_type(8))) short bf16x8;
typedef __attribute__((ext_vector_type(8))) unsigned short u16x8;

// ---- workspace layout (bytes) ----
static const size_t OFF_BF    = 0;                 // 147456
static const size_t OFF_T3    = 147456;            // 64 f32
static const size_t OFF_GLR   = 147712;            // [N][16] bf16, 3.2 MB
static const size_t OFF_PB    = 6547712;           // [N][56] bf16, 11.2 MB
static const size_t OFF_LQ    = 17747712;          // [N][56] bf16, 11.2 MB
static const size_t OFF_DENOM = 28947712;          // [N] f32
static const size_t OFF_NUMER = 29347712;          // [N] f32
static const size_t OFF_LLP   = 29747712;          // [NB_FUSED] f32
static const size_t OFF_CEP   = 29754112;          // [NB_CE] f32
static const size_t OFF_TKT   = 29755904;          // 1 u32 ticket

__device__ __forceinline__ ushort f2bf(float f) {
    union { float f; unsigned u; } v; v.f = f;
    unsigned r = v.u + 0x7fffu + ((v.u >> 16) & 1u);   // RNE
    return (ushort)(r >> 16);
}
__device__ __forceinline__ float bf2f(ushort b) {
    union { unsigned u; float f; } v; v.u = ((unsigned)b) << 16; return v.f;
}
__device__ __forceinline__ unsigned cvt_pk_bf16(float lo, float hi) {
    unsigned r;
    asm("v_cvt_pk_bf16_f32 %0, %1, %2" : "=v"(r) : "v"(lo), "v"(hi));
    return r;
}
__device__ __forceinline__ void gload16(const void* g, void* l) {
    __builtin_amdgcn_global_load_lds(
        (const __attribute__((address_space(1))) unsigned int*)g,
        (__attribute__((address_space(3))) unsigned int*)l,
        16, 0, 0);
}

// ---------- front: Bf (blocks<288) + t3 + zero (288..300) + softmax (301+) ----------
__global__ __launch_bounds__(256) void k_front(const float* __restrict__ Var,
                                               const float* __restrict__ Mu,
                                               const float* __restrict__ wl,
                                               const float* __restrict__ wr,
                                               const float* __restrict__ W,
                                               ushort* __restrict__ Bf,
                                               float* __restrict__ t3,
                                               float* __restrict__ P,
                                               ushort* __restrict__ Pb,
                                               ushort* __restrict__ LQ,
                                               unsigned* __restrict__ zeroed,
                                               unsigned* __restrict__ ticket) {
    if (blockIdx.x < 301) {
        // zeroing: denom+numer = 200000 words over 77056 threads
        int gid = blockIdx.x * 256 + threadIdx.x;
        for (int i = gid; i < 200000; i += 77056) zeroed[i] = 0u;
        if (gid == 0) *ticket = 0u;
    }
    if (blockIdx.x < 288) {
        int id = blockIdx.x * 256 + threadIdx.x;           // 0..73727 exact
        float v = 0.f;
        if (id < 65536) {
            int e    = id & 7;
            int lane = (id >> 3) & 63;
            int j    = (id >> 9) & 15;
            int kt   = id >> 13;
            int t    = j >> 1, ss = j & 1;
            int s    = kt * 2 + ss;
            int k    = s * 32 + ((lane >> 4) << 3) + e;
            int c    = (t & 3) * 16 + (lane & 15);
            if (k < N_GENES && c < N_CLASSES)
                v = (t < 4) ? 1.0f / Var[c * N_GENES + k]
                            : Mu[c * N_GENES + k] / Var[c * N_GENES + k];
        } else {
            int rem  = id - 65536;
            int e    = rem & 7;
            int lane = (rem >> 3) & 63;
            int s    = rem >> 9;              // 0..15
            int k    = s * 32 + ((lane >> 4) << 3) + e;
            int h    = lane & 15;
            if (k < N_GENES)
                v = (h < HID) ? wl[h * N_GENES + k] : wr[(h - HID) * N_GENES + k];
        }
        Bf[id] = f2bf(v);
    } else if (blockIdx.x < 301) {
        int c    = (blockIdx.x - 288) * 4 + (threadIdx.x >> 6);
        int lane = threadIdx.x & 63;
        if (c >= N_CLASSES) return;
        float s = 0.f;
        for (int g = lane; g < N_GENES; g += 64) {
            float m = Mu[c * N_GENES + g];
            s += m * m / Var[c * N_GENES + g];
        }
        #pragma unroll
        for (int off = 32; off; off >>= 1) s += __shfl_xor(s, off);
        if (lane == 0) t3[c] = s;
    } else {
        // softmax: 4 rows per block, 25000 blocks exactly
        int wid  = (blockIdx.x - 301) * 4 + (threadIdx.x >> 6);
        int lane = threadIdx.x & 63;
        float w = (lane < N_CLASSES) ? W[(size_t)wid * N_CLASSES + lane] : -__builtin_inff();
        float m = w;
        #pragma unroll
        for (int off = 32; off; off >>= 1) m = fmaxf(m, __shfl_xor(m, off));
        float e = (lane < N_CLASSES) ? expf(w - m) : 0.f;
        float s = e;
        #pragma unroll
        for (int off = 32; off; off >>= 1) s += __shfl_xor(s, off);
        float p = e / s;
        if (lane < N_CLASSES) P[(size_t)wid * N_CLASSES + lane] = p;
        if (lane < PROWS) {
            Pb[(size_t)wid * PROWS + lane] = (lane < N_CLASSES) ? f2bf(p) : 0;
            LQ[(size_t)wid * PROWS + lane] = (lane < N_CLASSES) ? f2bf(logf(p + 1e-8f)) : 0;
        }
    }
}

// ---------- fused MFMA (R7 verbatim, glr stored bf16) ----------
__global__ __launch_bounds__(256, 2) void k_fused(const float* __restrict__ X,
                                                  const float* __restrict__ S,
                                                  const float* __restrict__ P,
                                                  const ushort* __restrict__ Bf,
                                                  const float* __restrict__ t3,
                                                  const float* __restrict__ bl,
                                                  const float* __restrict__ br,
                                                  ushort* __restrict__ glrb,
                                                  float* __restrict__ llp) {
    __shared__ float  ldsA[2][4][16][16][4];   // 32 KB
    __shared__ ushort ldsB[2][20][64][8];      // 40 KB (18 real + 2 pad)
    __shared__ float  wsum[4];
    int tid  = threadIdx.x;
    int lane = tid & 63;
    int wv   = tid >> 6;
    int lhi  = lane >> 4;
    int slot = lane & 15;
    int rbase = blockIdx.x * 64 + wv * 16;
    const char* Xc  = (const char*)X;
    const char* Bfc = (const char*)Bf;

    int arow = rbase + slot;
    if (arow > N_CELLS - 1) arow = N_CELLS - 1;
    float m2s = -2.0f * S[arow];

    const f32x4 zz = {0.f, 0.f, 0.f, 0.f};
    f32x4 acc1[4], acc2[4], acc3;
    #pragma unroll
    for (int ct = 0; ct < 4; ++ct) { acc1[ct] = zz; acc2[ct] = zz; }
    acc3 = zz;

#define STAGE(KT, BUF) do {                                                        \
    _Pragma("unroll")                                                              \
    for (int i = 0; i < 4; ++i) {                                                  \
        int rloc = i * 4 + lhi;                                                    \
        int row  = rbase + rloc; if (row > N_CELLS - 1) row = N_CELLS - 1;         \
        int gi   = (KT) * 16 + (slot ^ (rloc & 7)); if (gi > 124) gi = 124;        \
        gload16(Xc + (size_t)row * 2000 + (size_t)gi * 16, &ldsA[BUF][wv][i * 4][0][0]); \
    }                                                                              \
    _Pragma("unroll")                                                              \
    for (int i = 0; i < 5; ++i) {                                                  \
        int j = wv * 5 + i;                                                        \
        size_t src;                                                                \
        if (j < 16)      src = (size_t)(KT) * 16384 + (size_t)j * 1024;            \
        else if (j < 18) src = 131072 + ((size_t)(KT) * 2 + (size_t)(j - 16)) * 1024; \
        else             src = (size_t)(KT) * 16384;                               \
        gload16(Bfc + src + (size_t)lane * 16, &ldsB[BUF][j][0][0]);               \
    }                                                                              \
} while (0)

    STAGE(0, 0);

    #pragma unroll
    for (int kt = 0; kt < NKT; ++kt) {
        const int cur = kt & 1;
        if (kt < NKT - 1) {
            STAGE(kt + 1, cur ^ 1);
            __builtin_amdgcn_sched_barrier(0);
            asm volatile("s_waitcnt vmcnt(9)" ::: "memory");
        } else {
            __builtin_amdgcn_sched_barrier(0);
            asm volatile("s_waitcnt vmcnt(0)" ::: "memory");
        }
        __builtin_amdgcn_sched_barrier(0);
        __builtin_amdgcn_s_barrier();
        __builtin_amdgcn_sched_barrier(0);

        const bf16x8* BL = (const bf16x8*)&ldsB[cur][0][0][0];
        #pragma unroll
        for (int ks = 0; ks < 2; ++ks) {
            int key = slot & 7;
            int c0  = ks * 8 + lhi * 2;
            f32x4 xa = *(const f32x4*)&ldsA[cur][wv][slot][c0 ^ key][0];
            f32x4 xb = *(const f32x4*)&ldsA[cur][wv][slot][(c0 + 1) ^ key][0];
            union { bf16x8 v; unsigned u[4]; } a1, a2;
            a1.u[0] = cvt_pk_bf16(xa[0] * xa[0], xa[1] * xa[1]);
            a1.u[1] = cvt_pk_bf16(xa[2] * xa[2], xa[3] * xa[3]);
            a1.u[2] = cvt_pk_bf16(xb[0] * xb[0], xb[1] * xb[1]);
            a1.u[3] = cvt_pk_bf16(xb[2] * xb[2], xb[3] * xb[3]);
            a2.u[0] = cvt_pk_bf16(m2s * xa[0], m2s * xa[1]);
            a2.u[1] = cvt_pk_bf16(m2s * xa[2], m2s * xa[3]);
            a2.u[2] = cvt_pk_bf16(m2s * xb[0], m2s * xb[1]);
            a2.u[3] = cvt_pk_bf16(m2s * xb[2], m2s * xb[3]);
            bf16x8 bg = BL[(16 + ks) * 64 + lane];
            #pragma unroll
            for (int ct = 0; ct < 4; ++ct)
                acc1[ct] = __builtin_amdgcn_mfma_f32_16x16x32_bf16(a1.v, BL[(ct * 2 + ks) * 64 + lane], acc1[ct], 0, 0, 0);
            #pragma unroll
            for (int ct = 0; ct < 4; ++ct)
                acc2[ct] = __builtin_amdgcn_mfma_f32_16x16x32_bf16(a2.v, BL[((4 + ct) * 2 + ks) * 64 + lane], acc2[ct], 0, 0, 0);
            acc3 = __builtin_amdgcn_mfma_f32_16x16x32_bf16(a2.v, bg, acc3, 0, 0, 0);
        }
        __builtin_amdgcn_sched_barrier(0);
        __builtin_amdgcn_s_barrier();
        __builtin_amdgcn_sched_barrier(0);
    }
#undef STAGE

    int col = lane & 15;
    int rg  = lane >> 4;
    float bias = (col < HID) ? bl[col] : br[col - HID];
    float part = 0.f;
    #pragma unroll
    for (int r = 0; r < 4; ++r) {
        int row = rbase + rg * 4 + r;
        if (row < N_CELLS) {
            float s2 = S[row];
            glrb[(size_t)row * 16 + col] = f2bf(acc3[r] / (-2.0f * s2) + bias);
            float ss = s2 * s2;
            #pragma unroll
            for (int ct = 0; ct < 4; ++ct) {
                int c = ct * 16 + col;
                if (c < N_CLASSES) {
                    float F = -0.5f * (acc1[ct][r] + acc2[ct][r] + ss * t3[c]);
                    part = fmaf(P[(size_t)row * N_CLASSES + c], F, part);
                }
            }
        }
    }
    #pragma unroll
    for (int off = 32; off; off >>= 1) part += __shfl_xor(part, off);
    if (lane == 0) wsum[wv] = part;
    __syncthreads();
    if (tid == 0) llp[blockIdx.x] = wsum[0] + wsum[1] + wsum[2] + wsum[3];
}

// ---------- fused edge pass: bf16 glr gathers ----------
__global__ __launch_bounds__(256) void k_edge(const int* __restrict__ ei,
                                              const ushort* __restrict__ glrb,
                                              const float* __restrict__ att,
                                              const ushort* __restrict__ Pb,
                                              const ushort* __restrict__ LQ,
                                              float* __restrict__ denom,
                                              float* __restrict__ numer) {
    int e = blockIdx.x * 256 + threadIdx.x;
    if (e >= N_EDGES) return;
    int src = ei[e], dst = ei[N_EDGES + e];
    u16x8 gv = *(const u16x8*)(glrb + (size_t)src * 16);       // gl[0..7]
    u16x8 hv = *(const u16x8*)(glrb + (size_t)dst * 16 + 8);   // gr[0..7]
    const float4* at = (const float4*)att;
    float4 a0 = at[0], a1 = at[1];
    float t, s = 0.f;
    t = bf2f(gv[0]) + bf2f(hv[0]); t = t > 0.f ? t : 0.2f * t; s = fmaf(a0.x, t, s);
    t = bf2f(gv[1]) + bf2f(hv[1]); t = t > 0.f ? t : 0.2f * t; s = fmaf(a0.y, t, s);
    t = bf2f(gv[2]) + bf2f(hv[2]); t = t > 0.f ? t : 0.2f * t; s = fmaf(a0.z, t, s);
    t = bf2f(gv[3]) + bf2f(hv[3]); t = t > 0.f ? t : 0.2f * t; s = fmaf(a0.w, t, s);
    t = bf2f(gv[4]) + bf2f(hv[4]); t = t > 0.f ? t : 0.2f * t; s = fmaf(a1.x, t, s);
    t = bf2f(gv[5]) + bf2f(hv[5]); t = t > 0.f ? t : 0.2f * t; s = fmaf(a1.y, t, s);
    t = bf2f(gv[6]) + bf2f(hv[6]); t = t > 0.f ? t : 0.2f * t; s = fmaf(a1.z, t, s);
    t = bf2f(gv[7]) + bf2f(hv[7]); t = t > 0.f ? t : 0.2f * t; s = fmaf(a1.w, t, s);
    float ex = expf(s);

    const u16x8* ps = (const u16x8*)(Pb + (size_t)src * PROWS);
    const u16x8* ld = (const u16x8*)(LQ + (size_t)dst * PROWS);
    float v = 0.f;
    #pragma unroll
    for (int i = 0; i < 7; ++i) {
        u16x8 pv = ps[i], lv = ld[i];
        #pragma unroll
        for (int j = 0; j < 8; ++j)
            v = fmaf(bf2f(pv[j]), bf2f(lv[j]), v);
    }
    atomicAdd(denom + dst, ex);
    atomicAdd(numer + dst, ex * v);
}

// ---------- CE node reduce + last-block final reduction ----------
__global__ __launch_bounds__(256) void k_ce_final(const float* __restrict__ denom,
                                                  const float* __restrict__ numer,
                                                  const float* __restrict__ llp,
                                                  float* __restrict__ cep,
                                                  unsigned* __restrict__ ticket,
                                                  float* __restrict__ out) {
    __shared__ float wsum[4];
    __shared__ unsigned lastv;
    __shared__ double l1[256], l2[256];
    int n = blockIdx.x * 256 + threadIdx.x;
    float v = 0.f;
    if (n < N_CELLS) {
        float d = denom[n];
        v = (d > 0.f) ? numer[n] / d : 0.f;
    }
    #pragma unroll
    for (int off = 32; off; off >>= 1) v += __shfl_xor(v, off);
    if ((threadIdx.x & 63) == 0) wsum[threadIdx.x >> 6] = v;
    __syncthreads();
    if (threadIdx.x == 0) {
        cep[blockIdx.x] = wsum[0] + wsum[1] + wsum[2] + wsum[3];
        __threadfence();                       // release cep store
        lastv = atomicAdd(ticket, 1u);
    }
    __syncthreads();
    if (lastv == NB_CE - 1) {                  // this block is last: do final reduce
        __threadfence();                       // acquire all cep stores
        int t = threadIdx.x;
        double s1 = 0.0, s2 = 0.0;
        for (int i = t; i < NB_FUSED; i += 256) s1 += (double)llp[i];
        for (int i = t; i < NB_CE; i += 256) s2 += (double)cep[i];
        l1[t] = s1; l2[t] = s2;
        __syncthreads();
        for (int off = 128; off; off >>= 1) {
            if (t < off) { l1[t] += l1[t + off]; l2[t] += l2[t + off]; }
            __syncthreads();
        }
        if (t == 0) {
            out[0] = (float)(l1[0] / (double)N_CELLS);
            out[1] = (float)(-l2[0] / (double)N_CELLS);
        }
    }
}

extern "C" void kernel_launch(void* const* d_in, const int* in_sizes, int n_in,
                              void* d_out, int out_size, void* d_ws, size_t ws_size,
                              hipStream_t stream) {
    const float* X   = (const float*)d_in[0];
    const float* Mu  = (const float*)d_in[1];
    const float* Var = (const float*)d_in[2];
    const float* W   = (const float*)d_in[3];
    const float* S   = (const float*)d_in[4];
    const int*   ei  = (const int*)d_in[5];
    const float* wl  = (const float*)d_in[6];
    const float* bl  = (const float*)d_in[7];
    const float* wr  = (const float*)d_in[8];
    const float* br  = (const float*)d_in[9];
    const float* att = (const float*)d_in[10];
    float* out = (float*)d_out;
    char*  ws  = (char*)d_ws;

    ushort*   Bf    = (ushort*)(ws + OFF_BF);
    float*    t3    = (float*)(ws + OFF_T3);
    ushort*   glrb  = (ushort*)(ws + OFF_GLR);
    ushort*   Pb    = (ushort*)(ws + OFF_PB);
    ushort*   LQ    = (ushort*)(ws + OFF_LQ);
    float*    denom = (float*)(ws + OFF_DENOM);
    float*    numer = (float*)(ws + OFF_NUMER);
    float*    llp   = (float*)(ws + OFF_LLP);
    float*    cep   = (float*)(ws + OFF_CEP);
    unsigned* tkt   = (unsigned*)(ws + OFF_TKT);
    float*    P     = out + 2;

    k_front   <<<301 + 25000, 256, 0, stream>>>(Var, Mu, wl, wr, W, Bf, t3, P, Pb, LQ,
                                                (unsigned*)(ws + OFF_DENOM), tkt);
    k_fused   <<<NB_FUSED, 256, 0, stream>>>(X, S, P, Bf, t3, bl, br, glrb, llp);
    k_edge    <<<(N_EDGES + 255) / 256, 256, 0, stream>>>(ei, glrb, att, Pb, LQ, denom, numer);
    k_ce_final<<<NB_CE, 256, 0, stream>>>(denom, numer, llp, cep, tkt, out);
}